// Round 10
// baseline (2197.801 us; speedup 1.0000x reference)
//
#include <hip/hip_runtime.h>

#define BATCH   8
#define NPTS    16384
#define NCH     128
#define NPOINT  1024
#define NSAMPLE 64
#define CIN     131   // 3 + NCH

#define THREADS  1024
#define TPP      16                 // points per thread (tile size)
#define CTAG     0x7C000000u

typedef unsigned long long u64;

__device__ __forceinline__ u64 u64max(u64 a, u64 b) { return a > b ? a : b; }

__device__ __forceinline__ u64 shfl_xor_u64(u64 v, int off) {
  const unsigned lo = __shfl_xor((unsigned)v, off, 64);
  const unsigned hi = __shfl_xor((unsigned)(v >> 32), off, 64);
  return ((u64)hi << 32) | lo;
}

// ---------------------------------------------------------------------------
// Per-batch spatial sort: Morton codes on a 16^3 grid over the batch bbox,
// bitonic-sorted in LDS (key = morton<<14 | orig). Output: sorig[b][pos] =
// original index. Intra-cell order is by orig index (key uniqueness) ->
// deterministic.
// ---------------------------------------------------------------------------
__global__ __launch_bounds__(1024) void sort_kernel(
    const float* __restrict__ xyz, int* __restrict__ sorig)
{
  const int b = blockIdx.x, t = threadIdx.x;
  const float* __restrict__ p = xyz + (size_t)b * NPTS * 3;
  __shared__ unsigned keys[NPTS];   // 64 KB

  float lx[16], ly[16], lz[16];
  float mnx = 1e30f, mxx = -1e30f, mny = 1e30f, mxy = -1e30f;
  float mnz = 1e30f, mxz = -1e30f;
#pragma unroll
  for (int i = 0; i < 16; ++i) {
    const int n = t + i * 1024;
    lx[i] = p[n * 3 + 0]; ly[i] = p[n * 3 + 1]; lz[i] = p[n * 3 + 2];
    mnx = fminf(mnx, lx[i]); mxx = fmaxf(mxx, lx[i]);
    mny = fminf(mny, ly[i]); mxy = fmaxf(mxy, ly[i]);
    mnz = fminf(mnz, lz[i]); mxz = fmaxf(mxz, lz[i]);
  }
#pragma unroll
  for (int off = 32; off >= 1; off >>= 1) {
    mnx = fminf(mnx, __shfl_xor(mnx, off, 64)); mxx = fmaxf(mxx, __shfl_xor(mxx, off, 64));
    mny = fminf(mny, __shfl_xor(mny, off, 64)); mxy = fmaxf(mxy, __shfl_xor(mxy, off, 64));
    mnz = fminf(mnz, __shfl_xor(mnz, off, 64)); mxz = fmaxf(mxz, __shfl_xor(mxz, off, 64));
  }
  if ((t & 63) == 0) {
    const int w = t >> 6;
    keys[w * 6 + 0] = __float_as_uint(mnx); keys[w * 6 + 1] = __float_as_uint(mxx);
    keys[w * 6 + 2] = __float_as_uint(mny); keys[w * 6 + 3] = __float_as_uint(mxy);
    keys[w * 6 + 4] = __float_as_uint(mnz); keys[w * 6 + 5] = __float_as_uint(mxz);
  }
  __syncthreads();
  if (t == 0) {
    float a0 = __uint_as_float(keys[0]), a1 = __uint_as_float(keys[1]);
    float a2 = __uint_as_float(keys[2]), a3 = __uint_as_float(keys[3]);
    float a4 = __uint_as_float(keys[4]), a5 = __uint_as_float(keys[5]);
    for (int w = 1; w < 16; ++w) {
      a0 = fminf(a0, __uint_as_float(keys[w * 6 + 0]));
      a1 = fmaxf(a1, __uint_as_float(keys[w * 6 + 1]));
      a2 = fminf(a2, __uint_as_float(keys[w * 6 + 2]));
      a3 = fmaxf(a3, __uint_as_float(keys[w * 6 + 3]));
      a4 = fminf(a4, __uint_as_float(keys[w * 6 + 4]));
      a5 = fmaxf(a5, __uint_as_float(keys[w * 6 + 5]));
    }
    keys[0] = __float_as_uint(a0); keys[1] = __float_as_uint(a1);
    keys[2] = __float_as_uint(a2); keys[3] = __float_as_uint(a3);
    keys[4] = __float_as_uint(a4); keys[5] = __float_as_uint(a5);
  }
  __syncthreads();
  const float bnx = __uint_as_float(keys[0]);
  const float bxx = __uint_as_float(keys[1]);
  const float bny = __uint_as_float(keys[2]);
  const float bxy = __uint_as_float(keys[3]);
  const float bnz = __uint_as_float(keys[4]);
  const float bxz = __uint_as_float(keys[5]);
  __syncthreads();   // bbox consumed before keys overwritten

  const float ivx = 15.9999f / fmaxf(bxx - bnx, 1e-20f);
  const float ivy = 15.9999f / fmaxf(bxy - bny, 1e-20f);
  const float ivz = 15.9999f / fmaxf(bxz - bnz, 1e-20f);
#pragma unroll
  for (int i = 0; i < 16; ++i) {
    const int n = t + i * 1024;
    int cx = (int)((lx[i] - bnx) * ivx);
    int cy = (int)((ly[i] - bny) * ivy);
    int cz = (int)((lz[i] - bnz) * ivz);
    cx = min(15, max(0, cx)); cy = min(15, max(0, cy)); cz = min(15, max(0, cz));
    unsigned m = 0;
#pragma unroll
    for (int j = 0; j < 4; ++j)
      m |= (((unsigned)(cx >> j) & 1u) << (3 * j))
         | (((unsigned)(cy >> j) & 1u) << (3 * j + 1))
         | (((unsigned)(cz >> j) & 1u) << (3 * j + 2));
    keys[n] = (m << 14) | (unsigned)n;
  }
  __syncthreads();

  for (unsigned kk = 2; kk <= (unsigned)NPTS; kk <<= 1) {
    for (unsigned j = kk >> 1; j > 0; j >>= 1) {
#pragma unroll
      for (int w = 0; w < 16; ++w) {
        const unsigned i = (unsigned)t + (unsigned)w * 1024u;
        const unsigned l = i ^ j;
        if (l > i) {
          const unsigned a = keys[i], c = keys[l];
          const bool asc = ((i & kk) == 0);
          if ((a > c) == asc) { keys[i] = c; keys[l] = a; }
        }
      }
      __syncthreads();
    }
  }

  for (int i = 0; i < 16; ++i) {
    const int pos = t + i * 1024;
    sorig[(size_t)b * NPTS + pos] = (int)(keys[pos] & 0x3FFFu);
  }
}

// ---------------------------------------------------------------------------
// Transpose weights into [ic][oc] layout (float4 loads in the MLP).
// ---------------------------------------------------------------------------
__global__ void wtrans_kernel(const float* __restrict__ W0,
                              const float* __restrict__ W1,
                              const float* __restrict__ W2,
                              float* __restrict__ w0t,
                              float* __restrict__ w1t,
                              float* __restrict__ w2t)
{
  const int t = blockIdx.x * blockDim.x + threadIdx.x;
  if (t < 64 * CIN) { const int oc = t / CIN, ic = t % CIN; w0t[ic * 64  + oc] = W0[t]; }
  if (t < 64 * 64)  { const int oc = t >> 6,  ic = t & 63;  w1t[ic * 64  + oc] = W1[t]; }
  if (t < 128 * 64) { const int oc = t / 64,  ic = t % 64;  w2t[ic * 128 + oc] = W2[t]; }
}

// ---------------------------------------------------------------------------
// Mega kernel. bids 0..7: FPS with exact tile pruning — thread owns 16
// spatially-adjacent (Morton-sorted) points; a tile is skipped iff
// LB(center, tile bbox)*(1-4e-6) >= tile max-mind (then min(mind,d)=mind
// bitwise for every point -> cached tile best stays exact). Updated tiles
// recompute with the EXACT reference formula (no-fma d, fminf, argmax
// first-occurrence by ORIGINAL index). bids 8..: one block per center:
// spin on tagged slot -> ballquery -> gather -> MLP -> maxpool (proven R9).
// ---------------------------------------------------------------------------
__global__ __launch_bounds__(THREADS) void mega_kernel(
    const float* __restrict__ xyz, const float* __restrict__ feat,
    const int* __restrict__ sorig,
    const float* __restrict__ w0t, const float* __restrict__ b0,
    const float* __restrict__ w1t, const float* __restrict__ b1,
    const float* __restrict__ w2t, const float* __restrict__ b2,
    float* __restrict__ out_newxyz, float* __restrict__ out_feat,
    float* __restrict__ out_inds_f, u64* __restrict__ cslot)
{
  __shared__ float sA[CIN * 64];     // grouped x (131x64); reused as h2
  __shared__ float sB[64 * 64];      // h1
  __shared__ int   s_idx[NSAMPLE];
  __shared__ int   bq[4][NSAMPLE];
  __shared__ int   bqcnt[4], bqfirst[4];
  __shared__ u64   s_w[2][16];
  __shared__ unsigned s_sel[4];

  const int t = threadIdx.x;

  if (blockIdx.x < BATCH) {
    // ======================= FPS path (exclusive CU) =======================
    const int b = blockIdx.x;
    const int lane = t & 63, wid = t >> 6;
    const float* __restrict__ p = xyz + (size_t)b * NPTS * 3;
    const int* __restrict__ so = sorig + (size_t)b * NPTS;

    int   oid[TPP];
    float xs[TPP], ys[TPP], zs[TPP], mind[TPP];
#pragma unroll
    for (int i = 0; i < TPP; ++i) oid[i] = so[t * TPP + i];
#pragma unroll
    for (int i = 0; i < TPP; ++i) {
      const int n = oid[i];
      xs[i] = p[n * 3 + 0]; ys[i] = p[n * 3 + 1]; zs[i] = p[n * 3 + 2];
      mind[i] = 1e10f;
    }
    // tile bbox
    float lox = xs[0], hix = xs[0], loy = ys[0], hiy = ys[0], loz = zs[0], hiz = zs[0];
#pragma unroll
    for (int i = 1; i < TPP; ++i) {
      lox = fminf(lox, xs[i]); hix = fmaxf(hix, xs[i]);
      loy = fminf(loy, ys[i]); hiy = fmaxf(hiy, ys[i]);
      loz = fminf(loz, zs[i]); hiz = fmaxf(hiz, zs[i]);
    }

    u64   cpk  = 0;
    float tmax = 1e10f;

    u64* __restrict__ cs = cslot + (size_t)b * NPOINT * 4;

    float px = p[0], py = p[1], pz = p[2];
    if (t == 0) {
      out_inds_f[b * NPOINT] = 0.0f;
      const size_t o = (size_t)b * NPOINT * 3;
      out_newxyz[o + 0] = px; out_newxyz[o + 1] = py; out_newxyz[o + 2] = pz;
      const u64 tg = (u64)CTAG << 32;
      __hip_atomic_store(&cs[1], tg | __float_as_uint(px), __ATOMIC_RELAXED, __HIP_MEMORY_SCOPE_AGENT);
      __hip_atomic_store(&cs[2], tg | __float_as_uint(py), __ATOMIC_RELAXED, __HIP_MEMORY_SCOPE_AGENT);
      __hip_atomic_store(&cs[3], tg | __float_as_uint(pz), __ATOMIC_RELAXED, __HIP_MEMORY_SCOPE_AGENT);
      __hip_atomic_store(&cs[0], tg | 0u, __ATOMIC_RELAXED, __HIP_MEMORY_SCOPE_AGENT);
    }

    for (int k = 1; k < NPOINT; ++k) {
      const int par = k & 1;

      // conservative bbox lower bound (any rounding; margin below covers it)
      const float ux = fmaxf(fmaxf(lox - px, px - hix), 0.f);
      const float uy = fmaxf(fmaxf(loy - py, py - hiy), 0.f);
      const float uz = fmaxf(fmaxf(loz - pz, pz - hiz), 0.f);
      const float lb = ux * ux + uy * uy + uz * uz;
      const bool need = (lb * 0.999996f < tmax);

      if (__ballot(need) != 0ull) {         // wave-coherent skip
        if (need) {
          float bestv = -1.0f;
          int   boid  = 0x7FFFFFFF;
#pragma unroll
          for (int i = 0; i < TPP; ++i) {
            const float dx = xs[i] - px;
            const float dy = ys[i] - py;
            const float dz = zs[i] - pz;
            // exact reference order, no fma contraction:
            const float d = __fadd_rn(__fadd_rn(__fmul_rn(dx, dx), __fmul_rn(dy, dy)),
                                      __fmul_rn(dz, dz));
            const float m = fminf(mind[i], d);
            mind[i] = m;
            const bool c = (m > bestv) || (m == bestv && oid[i] < boid);
            bestv = c ? m : bestv;
            boid  = c ? oid[i] : boid;
          }
          tmax = bestv;
          cpk  = ((u64)__float_as_uint(bestv) << 14) | (u64)(boid ^ 0x3FFF);
        }
      }

      // block argmax: u64-max == (val max, orig-idx min)
      u64 pk = cpk;
#pragma unroll
      for (int off = 32; off >= 1; off >>= 1) pk = u64max(pk, shfl_xor_u64(pk, off));
      if (lane == 0) s_w[par][wid] = pk;
      __syncthreads();

      u64 bw = s_w[par][0];
#pragma unroll
      for (int i = 1; i < 16; ++i) bw = u64max(bw, s_w[par][i]);
      const int bi = (int)((bw & 0x3FFF) ^ 0x3FFF);

      // uniform-address coord load (L2-broadcast)
      px = p[bi * 3 + 0]; py = p[bi * 3 + 1]; pz = p[bi * 3 + 2];

      if (t == 0) {
        out_inds_f[b * NPOINT + k] = (float)bi;
        const size_t o = ((size_t)b * NPOINT + k) * 3;
        out_newxyz[o + 0] = px; out_newxyz[o + 1] = py; out_newxyz[o + 2] = pz;
        const u64 tg = (u64)(CTAG | (unsigned)k) << 32;
        u64* __restrict__ ck = cs + (size_t)k * 4;
        __hip_atomic_store(&ck[1], tg | __float_as_uint(px), __ATOMIC_RELAXED, __HIP_MEMORY_SCOPE_AGENT);
        __hip_atomic_store(&ck[2], tg | __float_as_uint(py), __ATOMIC_RELAXED, __HIP_MEMORY_SCOPE_AGENT);
        __hip_atomic_store(&ck[3], tg | __float_as_uint(pz), __ATOMIC_RELAXED, __HIP_MEMORY_SCOPE_AGENT);
        __hip_atomic_store(&ck[0], tg | (unsigned)bi, __ATOMIC_RELAXED, __HIP_MEMORY_SCOPE_AGENT);
      }
      // no 2nd barrier: parity double-buffer on s_w
    }
    return;
  }

  // ======================= center path =======================
  const int c  = blockIdx.x - BATCH;
  const int b = c & 7, pc = c >> 3;            // pc-major: readiness ~ bid order
  const u64* __restrict__ cs = cslot + ((size_t)b * NPOINT + pc) * 4;

  if (t < 4) {
    const unsigned tg = CTAG | (unsigned)pc;
    u64 v;
    for (;;) {
      v = __hip_atomic_load(cs + t, __ATOMIC_RELAXED, __HIP_MEMORY_SCOPE_AGENT);
      if ((unsigned)(v >> 32) == tg) break;
      __builtin_amdgcn_s_sleep(8);
    }
    s_sel[t] = (unsigned)v;
  }
  __syncthreads();
  const float cx = __uint_as_float(s_sel[1]);
  const float cy = __uint_as_float(s_sel[2]);
  const float cz = __uint_as_float(s_sel[3]);
  const float* __restrict__ pb = xyz + (size_t)b * NPTS * 3;

  // ---- ball query: waves 0-3 scan disjoint quarters; exact first-64 merge.
  if (t < 256) {
    const int w = t >> 6, lane = t & 63;
    const float R2 = (float)(0.3 * 0.3);
    const int beg = w * (NPTS / 4);
    int cnt = 0, first = -1;
    for (int bs = beg; bs < beg + NPTS / 4; bs += 64) {
      const int n = bs + lane;
      const float dx = pb[n * 3 + 0] - cx;
      const float dy = pb[n * 3 + 1] - cy;
      const float dz = pb[n * 3 + 2] - cz;
      const float d = __fadd_rn(__fadd_rn(__fmul_rn(dx, dx), __fmul_rn(dy, dy)),
                                __fmul_rn(dz, dz));
      const bool in = d < R2;
      const u64 m = __ballot(in);
      if (first < 0 && m) first = bs + __ffsll(m) - 1;
      const int pos = __popcll(m & ((1ull << lane) - 1ull));
      if (in && cnt + pos < NSAMPLE) bq[w][cnt + pos] = n;
      cnt += __popcll(m);
      if (cnt >= NSAMPLE) break;
    }
    if (lane == 0) { bqcnt[w] = cnt < NSAMPLE ? cnt : NSAMPLE; bqfirst[w] = first; }
  }
  __syncthreads();
  if (t < NSAMPLE) {
    int firstAll = -1;
#pragma unroll
    for (int w = 0; w < 4; ++w)
      if (firstAll < 0 && bqfirst[w] >= 0) firstAll = bqfirst[w];
    int o = 0, val = -1;
#pragma unroll
    for (int w = 0; w < 4; ++w) {
      const int cw = bqcnt[w];
      if (val < 0 && t >= o && t < o + cw) val = bq[w][t - o];
      o += cw;
    }
    s_idx[t] = (val >= 0) ? val : firstAll;    // pad with first in-ball index
  }
  __syncthreads();

  // ---- grouping gather into LDS [ch][64] using all 16 waves
  const int sm = t & 63, cg = t >> 6;          // cg = 0..15
  const int is = s_idx[sm];
  if (cg == 0) {
    sA[0 * 64 + sm] = pb[is * 3 + 0] - cx;
    sA[1 * 64 + sm] = pb[is * 3 + 1] - cy;
    sA[2 * 64 + sm] = pb[is * 3 + 2] - cz;
  }
  const float* __restrict__ fb = feat + (size_t)b * NCH * NPTS;
  for (int ch = cg; ch < NCH; ch += 16)
    sA[(3 + ch) * 64 + sm] = fb[(size_t)ch * NPTS + is];
  __syncthreads();

  const int s0  = (t & 15) * 4;   // 4 samples
  const int oc0 = ((t >> 4) & 15) * 4;

  // ---- layer 1: CIN -> 64  (sA -> sB), waves 0-3
  if (t < 256) {
    float acc[4][4];
#pragma unroll
    for (int j = 0; j < 4; ++j) {
      const float bj = b0[oc0 + j];
#pragma unroll
      for (int i = 0; i < 4; ++i) acc[i][j] = bj;
    }
    for (int ic = 0; ic < CIN; ++ic) {
      const float4 xv = *(const float4*)&sA[ic * 64 + s0];
      const float4 wv = *(const float4*)&w0t[ic * 64 + oc0];
      const float xr[4] = {xv.x, xv.y, xv.z, xv.w};
      const float wr[4] = {wv.x, wv.y, wv.z, wv.w};
#pragma unroll
      for (int i = 0; i < 4; ++i)
#pragma unroll
        for (int j = 0; j < 4; ++j) acc[i][j] += xr[i] * wr[j];
    }
#pragma unroll
    for (int j = 0; j < 4; ++j) {
      float4 r;
      r.x = fmaxf(acc[0][j], 0.f); r.y = fmaxf(acc[1][j], 0.f);
      r.z = fmaxf(acc[2][j], 0.f); r.w = fmaxf(acc[3][j], 0.f);
      *(float4*)&sB[(oc0 + j) * 64 + s0] = r;
    }
  }
  __syncthreads();

  // ---- layer 2: 64 -> 64  (sB -> sA), waves 0-3
  if (t < 256) {
    float acc[4][4];
#pragma unroll
    for (int j = 0; j < 4; ++j) {
      const float bj = b1[oc0 + j];
#pragma unroll
      for (int i = 0; i < 4; ++i) acc[i][j] = bj;
    }
    for (int ic = 0; ic < 64; ++ic) {
      const float4 xv = *(const float4*)&sB[ic * 64 + s0];
      const float4 wv = *(const float4*)&w1t[ic * 64 + oc0];
      const float xr[4] = {xv.x, xv.y, xv.z, xv.w};
      const float wr[4] = {wv.x, wv.y, wv.z, wv.w};
#pragma unroll
      for (int i = 0; i < 4; ++i)
#pragma unroll
        for (int j = 0; j < 4; ++j) acc[i][j] += xr[i] * wr[j];
    }
#pragma unroll
    for (int j = 0; j < 4; ++j) {
      float4 r;
      r.x = fmaxf(acc[0][j], 0.f); r.y = fmaxf(acc[1][j], 0.f);
      r.z = fmaxf(acc[2][j], 0.f); r.w = fmaxf(acc[3][j], 0.f);
      *(float4*)&sA[(oc0 + j) * 64 + s0] = r;
    }
  }
  __syncthreads();

  // ---- layer 3: 64 -> 128 + max-pool over 64 samples, waves 0-3
  if (t < 256) {
    const int oc8 = ((t >> 4) & 15) * 8;
    float acc[4][8];
#pragma unroll
    for (int j = 0; j < 8; ++j) {
      const float bj = b2[oc8 + j];
#pragma unroll
      for (int i = 0; i < 4; ++i) acc[i][j] = bj;
    }
    for (int ic = 0; ic < 64; ++ic) {
      const float4 xv  = *(const float4*)&sA[ic * 64 + s0];
      const float4 wlo = *(const float4*)&w2t[ic * 128 + oc8];
      const float4 whi = *(const float4*)&w2t[ic * 128 + oc8 + 4];
      const float xr[4] = {xv.x, xv.y, xv.z, xv.w};
      const float wr[8] = {wlo.x, wlo.y, wlo.z, wlo.w, whi.x, whi.y, whi.z, whi.w};
#pragma unroll
      for (int i = 0; i < 4; ++i)
#pragma unroll
        for (int j = 0; j < 8; ++j) acc[i][j] += xr[i] * wr[j];
    }
    float m[8];
#pragma unroll
    for (int j = 0; j < 8; ++j)
      m[j] = fmaxf(fmaxf(acc[0][j], acc[1][j]), fmaxf(acc[2][j], acc[3][j]));
#pragma unroll
    for (int off = 8; off >= 1; off >>= 1) {
#pragma unroll
      for (int j = 0; j < 8; ++j)
        m[j] = fmaxf(m[j], __shfl_xor(m[j], off, 64));
    }
    if ((t & 15) == 0) {
#pragma unroll
      for (int j = 0; j < 8; ++j)
        out_feat[((size_t)b * NCH + oc8 + j) * NPOINT + pc] = fmaxf(m[j], 0.f);
    }
  }
}

// ---------------------------------------------------------------------------
extern "C" void kernel_launch(void* const* d_in, const int* in_sizes, int n_in,
                              void* d_out, int out_size, void* d_ws, size_t ws_size,
                              hipStream_t stream)
{
  const float* xyz  = (const float*)d_in[0];
  const float* feat = (const float*)d_in[1];
  const float* W0   = (const float*)d_in[2];
  const float* b0   = (const float*)d_in[3];
  const float* W1   = (const float*)d_in[4];
  const float* b1   = (const float*)d_in[5];
  const float* W2   = (const float*)d_in[6];
  const float* b2   = (const float*)d_in[7];

  float* out_newxyz = (float*)d_out;                               // 8*1024*3
  float* out_feat   = out_newxyz + (size_t)BATCH * NPOINT * 3;     // 8*128*1024
  float* out_inds_f = out_feat + (size_t)BATCH * NCH * NPOINT;     // 8*1024

  char* ws = (char*)d_ws;
  u64* cslot = (u64*)ws;                                // 8192*4 u64 = 256 KB
  int* sorig = (int*)(ws + 262144);                     // 8*16384 int = 512 KB
  float* w0t = (float*)(ws + 262144 + 524288);
  float* w1t = w0t + 64 * CIN;
  float* w2t = w1t + 64 * 64;

  hipMemsetAsync(cslot, 0, 262144, stream);             // clear center tags
  wtrans_kernel<<<dim3((64 * CIN + 255) / 256), dim3(256), 0, stream>>>(
      W0, W1, W2, w0t, w1t, w2t);
  sort_kernel<<<dim3(BATCH), dim3(1024), 0, stream>>>(xyz, sorig);
  mega_kernel<<<dim3(BATCH + BATCH * NPOINT), dim3(THREADS), 0, stream>>>(
      xyz, feat, sorig, w0t, b0, w1t, b1, w2t, b2,
      out_newxyz, out_feat, out_inds_f, cslot);
}